// Round 9
// baseline (300.211 us; speedup 1.0000x reference)
//
#include <hip/hip_runtime.h>
#include <hip/hip_fp16.h>
#include <cmath>

#define NNODES 100000
#define NEDGES 3200000
#define NFEAT 256
#define NCLASS 40

#define BSHIFT 8
#define BSIZE 256                                  // nodes per coarse bucket
#define NBUCK ((NNODES + BSIZE - 1) / BSIZE)       // 391
#define CAP 9216                                   // bucket capacity (mean 8192 + 11 sigma)
#define ECHUNK 8192
#define CSTH 512
#define EPT (ECHUNK / CSTH)                        // 16 edges per thread
#define NCB ((NEDGES + ECHUNK - 1) / ECHUNK)       // 391
#define EPTF (CAP / 512)                           // 18 staged edges per fine thread

// Intermediates are class-blocked fp16 slices (pre-scaled y' = dinv * y):
//   S0: classes 0..15  -> [NNODES][16] halves (32 B rows, 3.2 MB)
//   S1: classes 16..31 -> [NNODES][16] halves (32 B rows, 3.2 MB)
//   S2: classes 32..39 -> [NNODES][8]  halves (16 B rows, 1.6 MB)
// Each slice fits a 4 MiB per-XCD L2 -> hop gathers become L2 hits.
// CSR entry is packed u32: (src << 15) | (fp16(w) & 0x7FFF)  (w > 0).

using bf16x8 = __attribute__((ext_vector_type(8))) short;
using f32x4 = __attribute__((ext_vector_type(4))) float;

__device__ inline unsigned pk2(float a, float b) {
    __half2 h;
    h.x = __float2half_rn(a);
    h.y = __float2half_rn(b);
    return *reinterpret_cast<unsigned*>(&h);
}
__device__ inline float2 up2(unsigned u) {
    __half2 h = *reinterpret_cast<__half2*>(&u);
    float2 f;
    f.x = __half2float(h.x);
    f.y = __half2float(h.y);
    return f;
}
__device__ inline unsigned short f2bf(float f) {   // f32 -> bf16, round-nearest-even
    unsigned u = __float_as_uint(f);
    unsigned r = (u + 0x7FFFu + ((u >> 16) & 1u)) >> 16;
    return (unsigned short)r;
}

// ---------------------------------------------------------------------------
// Detect whether edge_index arrived as int64 (stride 2 in int32 units) or
// int32 (stride 1). int64 values < 2^31 have all-zero high dwords.
__global__ void detect_kernel(const int* __restrict__ eidx, int* __restrict__ flag) {
    __shared__ int odd_nz;
    if (threadIdx.x == 0) odd_nz = 0;
    __syncthreads();
    int local = 0;
    for (int i = threadIdx.x; i < 2048; i += blockDim.x) {
        if (eidx[2 * i + 1] != 0) local = 1;
    }
    if (local) atomicOr(&odd_nz, 1);
    __syncthreads();
    if (threadIdx.x == 0) *flag = odd_nz ? 1 : 2;
}

// ---------------------------------------------------------------------------
// Coarse scatter into fixed-capacity buckets [NBUCK][CAP]. Register-staged:
// eidx/ew read once; per-block LDS histogram reserves a contiguous run per
// bucket with ONE global atomic per (block, bucket). Packed entry:
//   .x = (src << BSHIFT) | (col & (BSIZE-1))   (17+8 bits < 32)
//   .y = float bits of edge weight
__global__ void __launch_bounds__(CSTH) cscatter_kernel(const int* __restrict__ eidx,
                                                        const float* __restrict__ ew,
                                                        int2* __restrict__ coarse,
                                                        int* __restrict__ cursor,
                                                        const int* __restrict__ flag) {
    __shared__ int h[NBUCK];
    __shared__ int lbase[NBUCK];
    int t = threadIdx.x;
    for (int i = t; i < NBUCK; i += CSTH) h[i] = 0;
    __syncthreads();
    int stride = *flag;
    long long cb = (long long)NEDGES * stride;
    int e0 = blockIdx.x * ECHUNK;
    int bk[EPT];
    int pk[EPT];
    float wv[EPT];
#pragma unroll
    for (int i = 0; i < EPT; i++) {
        int e = e0 + t + i * CSTH;
        if (e < NEDGES) {
            int col = eidx[cb + (long long)e * stride];
            int src = eidx[(long long)e * stride];
            wv[i] = ew[e];
            bk[i] = col >> BSHIFT;
            pk[i] = (src << BSHIFT) | (col & (BSIZE - 1));
            atomicAdd(&h[bk[i]], 1);
        } else {
            bk[i] = -1;
        }
    }
    __syncthreads();
    for (int i = t; i < NBUCK; i += CSTH) {
        int c = h[i];
        lbase[i] = c ? atomicAdd(&cursor[i], c) : 0;
        h[i] = 0;                      // reuse as local cursor
    }
    __syncthreads();
#pragma unroll
    for (int i = 0; i < EPT; i++) {
        if (bk[i] >= 0) {
            int pos = lbase[bk[i]] + atomicAdd(&h[bk[i]], 1);
            coarse[(size_t)bk[i] * CAP + pos] = make_int2(pk[i], __float_as_int(wv[i]));
        }
    }
}

// ---------------------------------------------------------------------------
// Fine pass: one block (512 thr) per bucket. Stages the whole bucket in
// registers, LDS-histograms by exact col, computes weighted degree -> dinv,
// writes rowmeta (begin,end in u32-CSR units) and permutes the bucket IN
// PLACE into packed-u32 CSR order.
__global__ void __launch_bounds__(512) fine_kernel(int2* __restrict__ coarse,
                                                   const int* __restrict__ cursor,
                                                   int2* __restrict__ rowmeta,
                                                   float* __restrict__ dinv) {
    __shared__ int hist[BSIZE];
    __shared__ float wdeg[BSIZE];
    __shared__ int foff[BSIZE];
    __shared__ int sa[BSIZE], sb[BSIZE];
    int t = threadIdx.x;
    int bk = blockIdx.x;
    size_t base = (size_t)bk * CAP;
    unsigned* csr32 = (unsigned*)coarse;           // in-place overlay
    int base2 = bk * CAP * 2;                      // bucket base in u32 units
    if (t < BSIZE) { hist[t] = 0; wdeg[t] = 0.f; }
    __syncthreads();
    int cnt = cursor[bk];
    int2 st[EPTF];
#pragma unroll
    for (int i = 0; i < EPTF; i++) {
        int idx = t + i * 512;
        if (idx < cnt) st[i] = coarse[base + idx];
    }
#pragma unroll
    for (int i = 0; i < EPTF; i++) {
        int idx = t + i * 512;
        if (idx < cnt) {
            int loc = st[i].x & (BSIZE - 1);
            atomicAdd(&hist[loc], 1);
            atomicAdd(&wdeg[loc], __int_as_float(st[i].y));
        }
    }
    __syncthreads();
    // dinv for this bucket's columns (deg + 1 self-loop)
    int gcol = (bk << BSHIFT) + t;
    if (t < BSIZE) {
        float dv = rsqrtf(wdeg[t] + 1.0f);
        if (gcol < NNODES) dinv[gcol] = dv;
        sa[t] = hist[t];
    }
    __syncthreads();
    // inclusive scan of hist (256 entries); all 512 threads hit barriers
    int* s = sa; int* d = sb;
    for (int off = 1; off < BSIZE; off <<= 1) {
        if (t < BSIZE) d[t] = s[t] + ((t >= off) ? s[t - off] : 0);
        __syncthreads();
        int* tmp = s; s = d; d = tmp;
    }
    if (t < BSIZE) {
        foff[t] = (t == 0) ? 0 : s[t - 1];
        hist[t] = 0;                               // reuse as fine cursor
        if (gcol < NNODES) rowmeta[gcol] = make_int2(base2 + foff[t], base2 + s[t]);
    }
    __syncthreads();
    // in-place permutation: all staged reads happened before this point
#pragma unroll
    for (int i = 0; i < EPTF; i++) {
        int idx = t + i * 512;
        if (idx < cnt) {
            int loc = st[i].x & (BSIZE - 1);
            unsigned srcn = ((unsigned)st[i].x) >> BSHIFT;
            int pos = foff[loc] + atomicAdd(&hist[loc], 1);
            unsigned wb = (unsigned)__half_as_ushort(__float2half_rn(__int_as_float(st[i].y))) & 0x7FFFu;
            csr32[base2 + pos] = (srcn << 15) | wb;
        }
    }
}

// ---------------------------------------------------------------------------
// W (f32 [40][256]) -> WT bf16 [48][256], classes 40..47 zero-padded.
__global__ void wconv_kernel(const float* __restrict__ W, unsigned short* __restrict__ wt) {
    int i = blockIdx.x * 256 + threadIdx.x;
    if (i >= 48 * 256) return;
    int n = i >> 8;
    wt[i] = (n < NCLASS) ? f2bf(W[i]) : (unsigned short)0;
}

// ---------------------------------------------------------------------------
// MFMA projection into class-blocked slices: Sk = fp16(dinv * (x @ W.T))[chunk k].
// Block = 4 waves; each wave: 16 nodes x 48 classes via 16x16x32 bf16 MFMA.
__global__ void __launch_bounds__(256) gemm_mfma_kernel(const float* __restrict__ x,
                                                        const unsigned short* __restrict__ wt,
                                                        const float* __restrict__ dinv,
                                                        __half* __restrict__ S0,
                                                        __half* __restrict__ S1,
                                                        __half* __restrict__ S2) {
    int wv = threadIdx.x >> 6;
    int lane = threadIdx.x & 63;
    int r = lane & 15;           // A row / B col within tile
    int kg = lane >> 4;          // k-group 0..3
    int mbase = blockIdx.x * 64 + wv * 16;
    int anode = mbase + r;
    bool aok = anode < NNODES;
    const float* ap = x + (size_t)anode * NFEAT + kg * 8;

    f32x4 acc0 = {0.f, 0.f, 0.f, 0.f};
    f32x4 acc1 = {0.f, 0.f, 0.f, 0.f};
    f32x4 acc2 = {0.f, 0.f, 0.f, 0.f};
#pragma unroll
    for (int ks = 0; ks < 8; ks++) {
        int k0 = ks * 32 + kg * 8;
        bf16x8 af;
        if (aok) {
            float4 p0 = *(const float4*)(ap + ks * 32);
            float4 p1 = *(const float4*)(ap + ks * 32 + 4);
            af[0] = (short)f2bf(p0.x); af[1] = (short)f2bf(p0.y);
            af[2] = (short)f2bf(p0.z); af[3] = (short)f2bf(p0.w);
            af[4] = (short)f2bf(p1.x); af[5] = (short)f2bf(p1.y);
            af[6] = (short)f2bf(p1.z); af[7] = (short)f2bf(p1.w);
        } else {
            af = bf16x8{0, 0, 0, 0, 0, 0, 0, 0};
        }
        bf16x8 b0 = *(const bf16x8*)(wt + (0 * 16 + r) * NFEAT + k0);
        bf16x8 b1 = *(const bf16x8*)(wt + (1 * 16 + r) * NFEAT + k0);
        bf16x8 b2 = *(const bf16x8*)(wt + (2 * 16 + r) * NFEAT + k0);
        acc0 = __builtin_amdgcn_mfma_f32_16x16x32_bf16(af, b0, acc0, 0, 0, 0);
        acc1 = __builtin_amdgcn_mfma_f32_16x16x32_bf16(af, b1, acc1, 0, 0, 0);
        acc2 = __builtin_amdgcn_mfma_f32_16x16x32_bf16(af, b2, acc2, 0, 0, 0);
    }
    // C/D layout: col(class) = lane&15, row(node) = (lane>>4)*4 + reg
#pragma unroll
    for (int j = 0; j < 4; j++) {
        int node = mbase + kg * 4 + j;
        if (node >= NNODES) continue;
        float dv = dinv[node];
        S0[(size_t)node * 16 + r] = __float2half_rn(acc0[j] * dv);
        S1[(size_t)node * 16 + r] = __float2half_rn(acc1[j] * dv);
        if (r < 8) S2[(size_t)node * 8 + r] = __float2half_rn(acc2[j] * dv);
    }
}

// ---------------------------------------------------------------------------
// Hop pass over one slice (LPN lanes/node, 8 classes = one uint4 per lane).
// acc = y'[self] + sum_e w_e * y'[src];  store fp16(dinv^2 * acc).
template <int LPN>
__global__ void __launch_bounds__(320) hopA_kernel(const int2* __restrict__ rowmeta,
                                                   const unsigned* __restrict__ csr,
                                                   const float* __restrict__ dinv,
                                                   const uint4* __restrict__ yin,
                                                   uint4* __restrict__ yout) {
    int idx = blockIdx.x * blockDim.x + threadIdx.x;
    int n = idx / LPN;
    int half = idx - n * LPN;
    if (n >= NNODES) return;
    float d = dinv[n];
    float dd = d * d;
    int2 rm = rowmeta[n];
    uint4 sv = yin[(size_t)n * LPN + half];
    float a0, a1, a2, a3, a4, a5, a6, a7;
    { float2 u0 = up2(sv.x), u1 = up2(sv.y), u2 = up2(sv.z), u3 = up2(sv.w);
      a0 = u0.x; a1 = u0.y; a2 = u1.x; a3 = u1.y; a4 = u2.x; a5 = u2.y; a6 = u3.x; a7 = u3.y; }
    int e = rm.x, e1 = rm.y;
    for (; e + 8 <= e1; e += 8) {
        unsigned p[8];
        uint4 g[8];
#pragma unroll
        for (int i = 0; i < 8; i++) p[i] = csr[e + i];
#pragma unroll
        for (int i = 0; i < 8; i++) g[i] = yin[(size_t)(p[i] >> 15) * LPN + half];
#pragma unroll
        for (int i = 0; i < 8; i++) {
            float w = __half2float(__ushort_as_half((unsigned short)(p[i] & 0x7FFFu)));
            float2 u0 = up2(g[i].x), u1 = up2(g[i].y), u2 = up2(g[i].z), u3 = up2(g[i].w);
            a0 += w * u0.x; a1 += w * u0.y; a2 += w * u1.x; a3 += w * u1.y;
            a4 += w * u2.x; a5 += w * u2.y; a6 += w * u3.x; a7 += w * u3.y;
        }
    }
    for (; e < e1; e++) {
        unsigned p = csr[e];
        uint4 g = yin[(size_t)(p >> 15) * LPN + half];
        float w = __half2float(__ushort_as_half((unsigned short)(p & 0x7FFFu)));
        float2 u0 = up2(g.x), u1 = up2(g.y), u2 = up2(g.z), u3 = up2(g.w);
        a0 += w * u0.x; a1 += w * u0.y; a2 += w * u1.x; a3 += w * u1.y;
        a4 += w * u2.x; a5 += w * u2.y; a6 += w * u3.x; a7 += w * u3.y;
    }
    uint4 o;
    o.x = pk2(dd * a0, dd * a1); o.y = pk2(dd * a2, dd * a3);
    o.z = pk2(dd * a4, dd * a5); o.w = pk2(dd * a6, dd * a7);
    yout[(size_t)n * LPN + half] = o;
}

// ---------------------------------------------------------------------------
// Final hop pass over one slice: writes raw logits dinv*acc + bias into
// out[n][cb + half*8 .. +8]; softmax runs afterwards.
template <int LPN>
__global__ void __launch_bounds__(320) hopB_kernel(const int2* __restrict__ rowmeta,
                                                   const unsigned* __restrict__ csr,
                                                   const float* __restrict__ dinv,
                                                   const uint4* __restrict__ yin,
                                                   const float* __restrict__ bias,
                                                   float* __restrict__ out, int cb) {
    int idx = blockIdx.x * blockDim.x + threadIdx.x;
    int n = idx / LPN;
    int half = idx - n * LPN;
    if (n >= NNODES) return;
    float d = dinv[n];
    int2 rm = rowmeta[n];
    uint4 sv = yin[(size_t)n * LPN + half];
    float a0, a1, a2, a3, a4, a5, a6, a7;
    { float2 u0 = up2(sv.x), u1 = up2(sv.y), u2 = up2(sv.z), u3 = up2(sv.w);
      a0 = u0.x; a1 = u0.y; a2 = u1.x; a3 = u1.y; a4 = u2.x; a5 = u2.y; a6 = u3.x; a7 = u3.y; }
    int e = rm.x, e1 = rm.y;
    for (; e + 8 <= e1; e += 8) {
        unsigned p[8];
        uint4 g[8];
#pragma unroll
        for (int i = 0; i < 8; i++) p[i] = csr[e + i];
#pragma unroll
        for (int i = 0; i < 8; i++) g[i] = yin[(size_t)(p[i] >> 15) * LPN + half];
#pragma unroll
        for (int i = 0; i < 8; i++) {
            float w = __half2float(__ushort_as_half((unsigned short)(p[i] & 0x7FFFu)));
            float2 u0 = up2(g[i].x), u1 = up2(g[i].y), u2 = up2(g[i].z), u3 = up2(g[i].w);
            a0 += w * u0.x; a1 += w * u0.y; a2 += w * u1.x; a3 += w * u1.y;
            a4 += w * u2.x; a5 += w * u2.y; a6 += w * u3.x; a7 += w * u3.y;
        }
    }
    for (; e < e1; e++) {
        unsigned p = csr[e];
        uint4 g = yin[(size_t)(p >> 15) * LPN + half];
        float w = __half2float(__ushort_as_half((unsigned short)(p & 0x7FFFu)));
        float2 u0 = up2(g.x), u1 = up2(g.y), u2 = up2(g.z), u3 = up2(g.w);
        a0 += w * u0.x; a1 += w * u0.y; a2 += w * u1.x; a3 += w * u1.y;
        a4 += w * u2.x; a5 += w * u2.y; a6 += w * u3.x; a7 += w * u3.y;
    }
    const float* bp = bias + cb + half * 8;
    float4 b0 = *(const float4*)bp;
    float4 b1 = *(const float4*)(bp + 4);
    float* op = out + (size_t)n * NCLASS + cb + half * 8;
    *(float4*)op = make_float4(d * a0 + b0.x, d * a1 + b0.y, d * a2 + b0.z, d * a3 + b0.w);
    *(float4*)(op + 4) = make_float4(d * a4 + b1.x, d * a5 + b1.y, d * a6 + b1.z, d * a7 + b1.w);
}

// ---------------------------------------------------------------------------
// In-place log_softmax over rows of 40 (bias already applied). One wave/row.
__global__ void softmax_kernel(float* __restrict__ out) {
    int gtid = blockIdx.x * blockDim.x + threadIdx.x;
    int wid = gtid >> 6;
    int lane = threadIdx.x & 63;
    if (wid >= NNODES) return;
    float* r = out + (size_t)wid * NCLASS;
    float v = (lane < NCLASS) ? r[lane] : -INFINITY;
    float m = v;
#pragma unroll
    for (int o = 32; o; o >>= 1) m = fmaxf(m, __shfl_xor(m, o));
    float e = (lane < NCLASS) ? __expf(v - m) : 0.f;
    float s = e;
#pragma unroll
    for (int o = 32; o; o >>= 1) s += __shfl_xor(s, o);
    if (lane < NCLASS) r[lane] = v - m - logf(s);
}

// ---------------------------------------------------------------------------
extern "C" void kernel_launch(void* const* d_in, const int* in_sizes, int n_in,
                              void* d_out, int out_size, void* d_ws, size_t ws_size,
                              hipStream_t stream) {
    const float* x = (const float*)d_in[0];
    const int* eidx = (const int*)d_in[1];
    const float* ew = (const float*)d_in[2];
    const float* W = (const float*)d_in[3];
    const float* b = (const float*)d_in[4];
    float* out = (float*)d_out;

    char* ws = (char*)d_ws;
    size_t off = 0;
    auto alloc = [&](size_t bytes) -> char* {
        char* p = ws + off;
        off += (bytes + 255) & ~(size_t)255;
        return p;
    };
    int* flag = (int*)alloc(sizeof(int));
    int* cursor = (int*)alloc((size_t)NBUCK * 4);
    int2* rowmeta = (int2*)alloc((size_t)NNODES * 8);
    float* dinv = (float*)alloc((size_t)NNODES * 4);
    unsigned short* wt = (unsigned short*)alloc((size_t)48 * 256 * 2);
    int2* gcsr = (int2*)alloc((size_t)NBUCK * CAP * 8);   // coarse -> packed u32 CSR in place
    __half* S0a = (__half*)alloc((size_t)NNODES * 32);
    __half* S1a = (__half*)alloc((size_t)NNODES * 32);
    __half* S2a = (__half*)alloc((size_t)NNODES * 16);
    __half* S0b = (__half*)alloc((size_t)NNODES * 32);
    __half* S1b = (__half*)alloc((size_t)NNODES * 32);
    __half* S2b = (__half*)alloc((size_t)NNODES * 16);

    hipMemsetAsync(cursor, 0, (size_t)NBUCK * 4, stream);
    detect_kernel<<<1, 256, 0, stream>>>(eidx, flag);
    wconv_kernel<<<48, 256, 0, stream>>>(W, wt);
    cscatter_kernel<<<NCB, CSTH, 0, stream>>>(eidx, ew, gcsr, cursor, flag);
    fine_kernel<<<NBUCK, 512, 0, stream>>>(gcsr, cursor, rowmeta, dinv);
    // project features first: y0' = dinv * (x @ W.T), class-blocked slices
    gemm_mfma_kernel<<<(NNODES + 63) / 64, 256, 0, stream>>>(x, wt, dinv, S0a, S1a, S2a);

    const unsigned* csr = (const unsigned*)gcsr;
    int g2 = (NNODES * 2 + 319) / 320;     // 625 blocks, LPN=2
    int g1 = (NNODES + 255) / 256;         // 391 blocks, LPN=1
    // per class-chunk: hop1 (slice a -> b) then hop2 (slice b -> logits)
    hopA_kernel<2><<<g2, 320, 0, stream>>>(rowmeta, csr, dinv, (const uint4*)S0a, (uint4*)S0b);
    hopB_kernel<2><<<g2, 320, 0, stream>>>(rowmeta, csr, dinv, (const uint4*)S0b, b, out, 0);
    hopA_kernel<2><<<g2, 320, 0, stream>>>(rowmeta, csr, dinv, (const uint4*)S1a, (uint4*)S1b);
    hopB_kernel<2><<<g2, 320, 0, stream>>>(rowmeta, csr, dinv, (const uint4*)S1b, b, out, 16);
    hopA_kernel<1><<<g1, 256, 0, stream>>>(rowmeta, csr, dinv, (const uint4*)S2a, (uint4*)S2b);
    hopB_kernel<1><<<g1, 256, 0, stream>>>(rowmeta, csr, dinv, (const uint4*)S2b, b, out, 32);
    // log_softmax over the completed logits
    softmax_kernel<<<(NNODES + 3) / 4, 256, 0, stream>>>(out);
}

// Round 10
// 221.580 us; speedup vs baseline: 1.3549x; 1.3549x over previous
//
#include <hip/hip_runtime.h>
#include <hip/hip_fp16.h>
#include <cmath>

#define NNODES 100000
#define NEDGES 3200000
#define NFEAT 256
#define NCLASS 40

#define BSHIFT 8
#define BSIZE 256                                  // nodes per coarse bucket
#define NBUCK ((NNODES + BSIZE - 1) / BSIZE)       // 391
#define CAP 10752                                  // bucket capacity incl. pad slack (21*512)
#define ECHUNK 8192
#define CSTH 512
#define EPT (ECHUNK / CSTH)                        // 16 edges per thread
#define NCB ((NEDGES + ECHUNK - 1) / ECHUNK)       // 391
#define EPTF (CAP / 512)                           // 21 staged edges per fine thread

// fp16 intermediate rows: 64 halves (128 B line), classes 0..39 used.
// Stored value is y' = dinv * y (pre-scaled).
// CSR entry is packed u32: (src << 15) | (fp16(w) & 0x7FFF), w > 0.
// Rows are padded to a multiple of 8 entries with (src=0, w=0) -> no hop tail.
#define ROWU2 16                                   // uint2 (4 halves) per 128 B row

using bf16x8 = __attribute__((ext_vector_type(8))) short;
using f32x4 = __attribute__((ext_vector_type(4))) float;

__device__ inline unsigned pk2(float a, float b) {
    __half2 h;
    h.x = __float2half_rn(a);
    h.y = __float2half_rn(b);
    return *reinterpret_cast<unsigned*>(&h);
}
__device__ inline float2 up2(unsigned u) {
    __half2 h = *reinterpret_cast<__half2*>(&u);
    float2 f;
    f.x = __half2float(h.x);
    f.y = __half2float(h.y);
    return f;
}
__device__ inline unsigned short f2bf(float f) {   // f32 -> bf16, round-nearest-even
    unsigned u = __float_as_uint(f);
    unsigned r = (u + 0x7FFFu + ((u >> 16) & 1u)) >> 16;
    return (unsigned short)r;
}

// ---------------------------------------------------------------------------
// Detect whether edge_index arrived as int64 (stride 2 in int32 units) or
// int32 (stride 1). int64 values < 2^31 have all-zero high dwords.
__global__ void detect_kernel(const int* __restrict__ eidx, int* __restrict__ flag) {
    __shared__ int odd_nz;
    if (threadIdx.x == 0) odd_nz = 0;
    __syncthreads();
    int local = 0;
    for (int i = threadIdx.x; i < 2048; i += blockDim.x) {
        if (eidx[2 * i + 1] != 0) local = 1;
    }
    if (local) atomicOr(&odd_nz, 1);
    __syncthreads();
    if (threadIdx.x == 0) *flag = odd_nz ? 1 : 2;
}

// ---------------------------------------------------------------------------
// Coarse scatter into fixed-capacity buckets [NBUCK][CAP]. Register-staged:
// eidx/ew read once; per-block LDS histogram reserves a contiguous run per
// bucket with ONE global atomic per (block, bucket). Packed entry:
//   .x = (src << BSHIFT) | (col & (BSIZE-1))   (17+8 bits < 32)
//   .y = float bits of edge weight
__global__ void __launch_bounds__(CSTH) cscatter_kernel(const int* __restrict__ eidx,
                                                        const float* __restrict__ ew,
                                                        int2* __restrict__ coarse,
                                                        int* __restrict__ cursor,
                                                        const int* __restrict__ flag) {
    __shared__ int h[NBUCK];
    __shared__ int lbase[NBUCK];
    int t = threadIdx.x;
    for (int i = t; i < NBUCK; i += CSTH) h[i] = 0;
    __syncthreads();
    int stride = *flag;
    long long cb = (long long)NEDGES * stride;
    int e0 = blockIdx.x * ECHUNK;
    int bk[EPT];
    int pk[EPT];
    float wv[EPT];
#pragma unroll
    for (int i = 0; i < EPT; i++) {
        int e = e0 + t + i * CSTH;
        if (e < NEDGES) {
            int col = eidx[cb + (long long)e * stride];
            int src = eidx[(long long)e * stride];
            wv[i] = ew[e];
            bk[i] = col >> BSHIFT;
            pk[i] = (src << BSHIFT) | (col & (BSIZE - 1));
            atomicAdd(&h[bk[i]], 1);
        } else {
            bk[i] = -1;
        }
    }
    __syncthreads();
    for (int i = t; i < NBUCK; i += CSTH) {
        int c = h[i];
        lbase[i] = c ? atomicAdd(&cursor[i], c) : 0;
        h[i] = 0;                      // reuse as local cursor
    }
    __syncthreads();
#pragma unroll
    for (int i = 0; i < EPT; i++) {
        if (bk[i] >= 0) {
            int pos = lbase[bk[i]] + atomicAdd(&h[bk[i]], 1);
            coarse[(size_t)bk[i] * CAP + pos] = make_int2(pk[i], __float_as_int(wv[i]));
        }
    }
}

// ---------------------------------------------------------------------------
// Fine pass: one block (512 thr) per bucket. Stages the bucket in registers,
// LDS-histograms by exact col, computes weighted degree -> dinv, writes
// rowmeta (begin, padded end) and permutes IN PLACE into packed-u32 CSR,
// padding each row to a multiple of 8 with zero entries.
__global__ void __launch_bounds__(512) fine_kernel(int2* __restrict__ coarse,
                                                   const int* __restrict__ cursor,
                                                   int2* __restrict__ rowmeta,
                                                   float* __restrict__ dinv) {
    __shared__ int hist[BSIZE];
    __shared__ float wdeg[BSIZE];
    __shared__ int foff[BSIZE];
    __shared__ int sa[BSIZE], sb[BSIZE];
    int t = threadIdx.x;
    int bk = blockIdx.x;
    size_t base = (size_t)bk * CAP;
    unsigned* csr32 = (unsigned*)coarse;           // in-place overlay
    int base2 = bk * CAP * 2;                      // bucket base in u32 units
    if (t < BSIZE) { hist[t] = 0; wdeg[t] = 0.f; }
    __syncthreads();
    int cnt = cursor[bk];
    int2 st[EPTF];
#pragma unroll
    for (int i = 0; i < EPTF; i++) {
        int idx = t + i * 512;
        if (idx < cnt) st[i] = coarse[base + idx];
    }
#pragma unroll
    for (int i = 0; i < EPTF; i++) {
        int idx = t + i * 512;
        if (idx < cnt) {
            int loc = st[i].x & (BSIZE - 1);
            atomicAdd(&hist[loc], 1);
            atomicAdd(&wdeg[loc], __int_as_float(st[i].y));
        }
    }
    __syncthreads();
    // dinv (deg + 1 self-loop); padded per-col counts for the scan
    int gcol = (bk << BSHIFT) + t;
    int hreal = 0, hpad = 0;
    if (t < BSIZE) {
        float dv = rsqrtf(wdeg[t] + 1.0f);
        if (gcol < NNODES) dinv[gcol] = dv;
        hreal = hist[t];
        hpad = (hreal + 7) & ~7;
        sa[t] = hpad;
    }
    __syncthreads();
    // inclusive scan of padded counts (256 entries); all 512 threads barrier
    int* s = sa; int* d = sb;
    for (int off = 1; off < BSIZE; off <<= 1) {
        if (t < BSIZE) d[t] = s[t] + ((t >= off) ? s[t - off] : 0);
        __syncthreads();
        int* tmp = s; s = d; d = tmp;
    }
    if (t < BSIZE) {
        foff[t] = (t == 0) ? 0 : s[t - 1];
        hist[t] = 0;                               // reuse as fine cursor
        if (gcol < NNODES) rowmeta[gcol] = make_int2(base2 + foff[t], base2 + foff[t] + hpad);
        for (int k = hreal; k < hpad; k++)         // zero-pad tail slots (src=0, w=0)
            csr32[base2 + foff[t] + k] = 0u;
    }
    __syncthreads();
    // in-place permutation: all staged reads happened before this point
#pragma unroll
    for (int i = 0; i < EPTF; i++) {
        int idx = t + i * 512;
        if (idx < cnt) {
            int loc = st[i].x & (BSIZE - 1);
            unsigned srcn = ((unsigned)st[i].x) >> BSHIFT;
            int pos = foff[loc] + atomicAdd(&hist[loc], 1);
            unsigned wb = (unsigned)__half_as_ushort(__float2half_rn(__int_as_float(st[i].y))) & 0x7FFFu;
            csr32[base2 + pos] = (srcn << 15) | wb;
        }
    }
}

// ---------------------------------------------------------------------------
// W (f32 [40][256]) -> WT bf16 [48][256], classes 40..47 zero-padded.
__global__ void wconv_kernel(const float* __restrict__ W, unsigned short* __restrict__ wt) {
    int i = blockIdx.x * 256 + threadIdx.x;
    if (i >= 48 * 256) return;
    int n = i >> 8;
    wt[i] = (n < NCLASS) ? f2bf(W[i]) : (unsigned short)0;
}

// ---------------------------------------------------------------------------
// MFMA projection: y0h[n, 0..39] = fp16( dinv[n] * (x[n,:] @ WT^T) ).
// Block = 4 waves; each wave: 16 nodes x 48 classes via 16x16x32 bf16 MFMA.
__global__ void __launch_bounds__(256) gemm_mfma_kernel(const float* __restrict__ x,
                                                        const unsigned short* __restrict__ wt,
                                                        const float* __restrict__ dinv,
                                                        __half* __restrict__ y0h) {
    int wv = threadIdx.x >> 6;
    int lane = threadIdx.x & 63;
    int r = lane & 15;           // A row / B col within tile
    int kg = lane >> 4;          // k-group 0..3
    int mbase = blockIdx.x * 64 + wv * 16;
    int anode = mbase + r;
    bool aok = anode < NNODES;
    const float* ap = x + (size_t)anode * NFEAT + kg * 8;

    f32x4 acc0 = {0.f, 0.f, 0.f, 0.f};
    f32x4 acc1 = {0.f, 0.f, 0.f, 0.f};
    f32x4 acc2 = {0.f, 0.f, 0.f, 0.f};
#pragma unroll
    for (int ks = 0; ks < 8; ks++) {
        int k0 = ks * 32 + kg * 8;
        bf16x8 af;
        if (aok) {
            float4 p0 = *(const float4*)(ap + ks * 32);
            float4 p1 = *(const float4*)(ap + ks * 32 + 4);
            af[0] = (short)f2bf(p0.x); af[1] = (short)f2bf(p0.y);
            af[2] = (short)f2bf(p0.z); af[3] = (short)f2bf(p0.w);
            af[4] = (short)f2bf(p1.x); af[5] = (short)f2bf(p1.y);
            af[6] = (short)f2bf(p1.z); af[7] = (short)f2bf(p1.w);
        } else {
            af = bf16x8{0, 0, 0, 0, 0, 0, 0, 0};
        }
        bf16x8 b0 = *(const bf16x8*)(wt + (0 * 16 + r) * NFEAT + k0);
        bf16x8 b1 = *(const bf16x8*)(wt + (1 * 16 + r) * NFEAT + k0);
        bf16x8 b2 = *(const bf16x8*)(wt + (2 * 16 + r) * NFEAT + k0);
        acc0 = __builtin_amdgcn_mfma_f32_16x16x32_bf16(af, b0, acc0, 0, 0, 0);
        acc1 = __builtin_amdgcn_mfma_f32_16x16x32_bf16(af, b1, acc1, 0, 0, 0);
        acc2 = __builtin_amdgcn_mfma_f32_16x16x32_bf16(af, b2, acc2, 0, 0, 0);
    }
    // C/D layout: col(class) = lane&15, row(node) = (lane>>4)*4 + reg
#pragma unroll
    for (int j = 0; j < 4; j++) {
        int node = mbase + kg * 4 + j;
        if (node >= NNODES) continue;
        float dv = dinv[node];
        __half* yr = y0h + (size_t)node * 64;
        yr[r] = __float2half_rn(acc0[j] * dv);
        yr[16 + r] = __float2half_rn(acc1[j] * dv);
        if (r < 8) yr[32 + r] = __float2half_rn(acc2[j] * dv);
    }
}

// ---------------------------------------------------------------------------
// Hop (y' in / y' out): thread = (node, 4 classes), 10 lanes x uint2 per row.
// Block = 320 thr = 32 nodes. Rows are 8-padded -> single 8-deep body, no tail.
// acc = y'[self] + sum_e w_e * y'[src];  store fp16(dinv^2 * acc).
__global__ void __launch_bounds__(320) hop16_kernel(const int2* __restrict__ rowmeta,
                                                    const unsigned* __restrict__ csr,
                                                    const float* __restrict__ dinv,
                                                    const uint2* __restrict__ yin,
                                                    uint2* __restrict__ yout) {
    int tid = threadIdx.x;
    int ln = tid / 10;
    int c4 = tid - ln * 10;
    int n = blockIdx.x * 32 + ln;                  // NNODES == 3125*32, no tail
    float d = dinv[n];
    float dd = d * d;
    int2 rm = rowmeta[n];
    uint2 sv = yin[(size_t)n * ROWU2 + c4];
    float2 s01 = up2(sv.x), s23 = up2(sv.y);
    float a0 = s01.x, a1 = s01.y, a2 = s23.x, a3 = s23.y;
    for (int e = rm.x; e < rm.y; e += 8) {
        unsigned p[8];
        uint2 g[8];
#pragma unroll
        for (int i = 0; i < 8; i++) p[i] = csr[e + i];
#pragma unroll
        for (int i = 0; i < 8; i++) g[i] = yin[(size_t)(p[i] >> 15) * ROWU2 + c4];
#pragma unroll
        for (int i = 0; i < 8; i++) {
            float w = __half2float(__ushort_as_half((unsigned short)(p[i] & 0x7FFFu)));
            float2 u = up2(g[i].x), v = up2(g[i].y);
            a0 += w * u.x; a1 += w * u.y; a2 += w * v.x; a3 += w * v.y;
        }
    }
    yout[(size_t)n * ROWU2 + c4] = make_uint2(pk2(dd * a0, dd * a1), pk2(dd * a2, dd * a3));
}

// ---------------------------------------------------------------------------
// Final hop (y' in / f32 out) with bias + log_softmax fused.
__global__ void __launch_bounds__(320) hop32_kernel(const int2* __restrict__ rowmeta,
                                                    const unsigned* __restrict__ csr,
                                                    const float* __restrict__ dinv,
                                                    const uint2* __restrict__ yin,
                                                    const float* __restrict__ bias,
                                                    float* __restrict__ out) {
    __shared__ float redm[32][10];
    __shared__ float reds[32][10];
    int tid = threadIdx.x;
    int ln = tid / 10;
    int c4 = tid - ln * 10;
    int n = blockIdx.x * 32 + ln;                  // NNODES == 3125*32, no tail
    float d = dinv[n];
    int2 rm = rowmeta[n];
    uint2 sv = yin[(size_t)n * ROWU2 + c4];
    float2 s01 = up2(sv.x), s23 = up2(sv.y);
    float a0 = s01.x, a1 = s01.y, a2 = s23.x, a3 = s23.y;
    for (int e = rm.x; e < rm.y; e += 8) {
        unsigned p[8];
        uint2 g[8];
#pragma unroll
        for (int i = 0; i < 8; i++) p[i] = csr[e + i];
#pragma unroll
        for (int i = 0; i < 8; i++) g[i] = yin[(size_t)(p[i] >> 15) * ROWU2 + c4];
#pragma unroll
        for (int i = 0; i < 8; i++) {
            float w = __half2float(__ushort_as_half((unsigned short)(p[i] & 0x7FFFu)));
            float2 u = up2(g[i].x), v = up2(g[i].y);
            a0 += w * u.x; a1 += w * u.y; a2 += w * v.x; a3 += w * v.y;
        }
    }
    // logits = dinv * acc + bias
    float4 bb = *(const float4*)(bias + c4 * 4);
    float v0 = d * a0 + bb.x, v1 = d * a1 + bb.y, v2 = d * a2 + bb.z, v3 = d * a3 + bb.w;
    // log_softmax over the node's 40 classes (10 lanes x 4)
    redm[ln][c4] = fmaxf(fmaxf(v0, v1), fmaxf(v2, v3));
    __syncthreads();
    if (c4 == 0) {
        float m = redm[ln][0];
#pragma unroll
        for (int j = 1; j < 10; j++) m = fmaxf(m, redm[ln][j]);
        redm[ln][0] = m;
    }
    __syncthreads();
    float m = redm[ln][0];
    reds[ln][c4] = __expf(v0 - m) + __expf(v1 - m) + __expf(v2 - m) + __expf(v3 - m);
    __syncthreads();
    if (c4 == 0) {
        float s = 0.f;
#pragma unroll
        for (int j = 0; j < 10; j++) s += reds[ln][j];
        reds[ln][0] = logf(s);
    }
    __syncthreads();
    float ls = reds[ln][0];
    float4 r = make_float4(v0 - m - ls, v1 - m - ls, v2 - m - ls, v3 - m - ls);
    *(float4*)(out + (size_t)n * NCLASS + c4 * 4) = r;
}

// ---------------------------------------------------------------------------
extern "C" void kernel_launch(void* const* d_in, const int* in_sizes, int n_in,
                              void* d_out, int out_size, void* d_ws, size_t ws_size,
                              hipStream_t stream) {
    const float* x = (const float*)d_in[0];
    const int* eidx = (const int*)d_in[1];
    const float* ew = (const float*)d_in[2];
    const float* W = (const float*)d_in[3];
    const float* b = (const float*)d_in[4];
    float* out = (float*)d_out;

    char* ws = (char*)d_ws;
    size_t off = 0;
    auto alloc = [&](size_t bytes) -> char* {
        char* p = ws + off;
        off += (bytes + 255) & ~(size_t)255;
        return p;
    };
    int* flag = (int*)alloc(sizeof(int));
    int* cursor = (int*)alloc((size_t)NBUCK * 4);
    int2* rowmeta = (int2*)alloc((size_t)NNODES * 8);
    float* dinv = (float*)alloc((size_t)NNODES * 4);
    unsigned short* wt = (unsigned short*)alloc((size_t)48 * 256 * 2);
    int2* gcsr = (int2*)alloc((size_t)NBUCK * CAP * 8);   // coarse -> packed u32 CSR in place
    __half* y0h = (__half*)alloc((size_t)NNODES * 128);
    __half* y1h = (__half*)alloc((size_t)NNODES * 128);

    hipMemsetAsync(cursor, 0, (size_t)NBUCK * 4, stream);
    detect_kernel<<<1, 256, 0, stream>>>(eidx, flag);
    wconv_kernel<<<48, 256, 0, stream>>>(W, wt);
    cscatter_kernel<<<NCB, CSTH, 0, stream>>>(eidx, ew, gcsr, cursor, flag);
    fine_kernel<<<NBUCK, 512, 0, stream>>>(gcsr, cursor, rowmeta, dinv);
    // project features first: y0' = dinv * (x @ W.T)  (propagation commutes)
    gemm_mfma_kernel<<<(NNODES + 63) / 64, 256, 0, stream>>>(x, wt, dinv, y0h);
    const unsigned* csr = (const unsigned*)gcsr;
    // hop 1: y1' = dinv^2 (y0'[self] + A_w y0');  hop 2: out = log_softmax(dinv(...) + b)
    hop16_kernel<<<NNODES / 32, 320, 0, stream>>>(rowmeta, csr, dinv,
                                                  (const uint2*)y0h, (uint2*)y1h);
    hop32_kernel<<<NNODES / 32, 320, 0, stream>>>(rowmeta, csr, dinv,
                                                  (const uint2*)y1h, b, out);
}

// Round 11
// 210.733 us; speedup vs baseline: 1.4246x; 1.0515x over previous
//
#include <hip/hip_runtime.h>
#include <hip/hip_fp16.h>
#include <cmath>

#define NNODES 100000
#define NEDGES 3200000
#define NFEAT 256
#define NCLASS 40

#define BSHIFT 8
#define BSIZE 256                                  // nodes per coarse bucket
#define NBUCK ((NNODES + BSIZE - 1) / BSIZE)       // 391
#define CAP 11264                                  // bucket capacity (11*1024, incl pad slack)
#define ECHUNK 16384
#define CSTH 1024
#define EPT (ECHUNK / CSTH)                        // 16 edges per thread
#define NCB ((NEDGES + ECHUNK - 1) / ECHUNK)       // 196
#define FTH 1024
#define EPTF (CAP / FTH)                           // 11 staged edges per fine thread

// fp16 intermediate rows: 64 halves (128 B line), classes 0..39 used.
// Stored value is y' = dinv * y (pre-scaled).
// CSR entry is packed u32: (src << 15) | (fp16(w) & 0x7FFF), w > 0.
// Rows are padded to a multiple of 8 entries with (src=0, w=0) -> no hop tail.
#define ROWU2 16                                   // uint2 (4 halves) per 128 B row

using bf16x8 = __attribute__((ext_vector_type(8))) short;
using f32x4 = __attribute__((ext_vector_type(4))) float;

__device__ inline unsigned pk2(float a, float b) {
    __half2 h;
    h.x = __float2half_rn(a);
    h.y = __float2half_rn(b);
    return *reinterpret_cast<unsigned*>(&h);
}
__device__ inline float2 up2(unsigned u) {
    __half2 h = *reinterpret_cast<__half2*>(&u);
    float2 f;
    f.x = __half2float(h.x);
    f.y = __half2float(h.y);
    return f;
}
__device__ inline unsigned short f2bf(float f) {   // f32 -> bf16, round-nearest-even
    unsigned u = __float_as_uint(f);
    unsigned r = (u + 0x7FFFu + ((u >> 16) & 1u)) >> 16;
    return (unsigned short)r;
}

// ---------------------------------------------------------------------------
// Fused setup: blocks 0..47 convert W -> bf16 WT[48][256] (zero-padded);
// block 48 zeros the bucket cursors; block 49 detects int64-vs-int32
// edge_index (int64 data read as int32 has all-zero high dwords).
__global__ void __launch_bounds__(256) setup_kernel(const float* __restrict__ W,
                                                    unsigned short* __restrict__ wt,
                                                    int* __restrict__ cursor,
                                                    const int* __restrict__ eidx,
                                                    int* __restrict__ flag) {
    int bk = blockIdx.x;
    int t = threadIdx.x;
    if (bk < 48) {
        int i = bk * 256 + t;
        int n = i >> 8;
        wt[i] = (n < NCLASS) ? f2bf(W[i]) : (unsigned short)0;
    } else if (bk == 48) {
        for (int i = t; i < NBUCK; i += 256) cursor[i] = 0;
    } else {
        __shared__ int odd_nz;
        if (t == 0) odd_nz = 0;
        __syncthreads();
        int local = 0;
        for (int i = t; i < 2048; i += 256) {
            if (eidx[2 * i + 1] != 0) local = 1;
        }
        if (local) atomicOr(&odd_nz, 1);
        __syncthreads();
        if (t == 0) *flag = odd_nz ? 1 : 2;
    }
}

// ---------------------------------------------------------------------------
// Coarse scatter into fixed-capacity buckets [NBUCK][CAP]. Register-staged:
// eidx/ew read once; per-block LDS histogram reserves a contiguous run per
// bucket with ONE global atomic per (block, bucket). Packed entry:
//   .x = (src << BSHIFT) | (col & (BSIZE-1))   (17+8 bits < 32)
//   .y = float bits of edge weight
__global__ void __launch_bounds__(CSTH) cscatter_kernel(const int* __restrict__ eidx,
                                                        const float* __restrict__ ew,
                                                        int2* __restrict__ coarse,
                                                        int* __restrict__ cursor,
                                                        const int* __restrict__ flag) {
    __shared__ int h[NBUCK];
    __shared__ int lbase[NBUCK];
    int t = threadIdx.x;
    for (int i = t; i < NBUCK; i += CSTH) h[i] = 0;
    __syncthreads();
    int stride = *flag;
    long long cb = (long long)NEDGES * stride;
    int e0 = blockIdx.x * ECHUNK;
    int bk[EPT];
    int pk[EPT];
    float wv[EPT];
#pragma unroll
    for (int i = 0; i < EPT; i++) {
        int e = e0 + t + i * CSTH;
        if (e < NEDGES) {
            int col = eidx[cb + (long long)e * stride];
            int src = eidx[(long long)e * stride];
            wv[i] = ew[e];
            bk[i] = col >> BSHIFT;
            pk[i] = (src << BSHIFT) | (col & (BSIZE - 1));
            atomicAdd(&h[bk[i]], 1);
        } else {
            bk[i] = -1;
        }
    }
    __syncthreads();
    for (int i = t; i < NBUCK; i += CSTH) {
        int c = h[i];
        lbase[i] = c ? atomicAdd(&cursor[i], c) : 0;
        h[i] = 0;                      // reuse as local cursor
    }
    __syncthreads();
#pragma unroll
    for (int i = 0; i < EPT; i++) {
        if (bk[i] >= 0) {
            int pos = lbase[bk[i]] + atomicAdd(&h[bk[i]], 1);
            coarse[(size_t)bk[i] * CAP + pos] = make_int2(pk[i], __float_as_int(wv[i]));
        }
    }
}

// ---------------------------------------------------------------------------
// Fine pass: one block (1024 thr) per bucket. Stages the bucket in registers,
// LDS-histograms by exact col, computes weighted degree -> dinv, writes
// rowmeta (begin, padded end) and permutes IN PLACE into packed-u32 CSR,
// padding each row to a multiple of 8 with zero entries.
__global__ void __launch_bounds__(FTH) fine_kernel(int2* __restrict__ coarse,
                                                   const int* __restrict__ cursor,
                                                   int2* __restrict__ rowmeta,
                                                   float* __restrict__ dinv) {
    __shared__ int hist[BSIZE];
    __shared__ float wdeg[BSIZE];
    __shared__ int foff[BSIZE];
    __shared__ int sa[BSIZE], sb[BSIZE];
    int t = threadIdx.x;
    int bk = blockIdx.x;
    size_t base = (size_t)bk * CAP;
    unsigned* csr32 = (unsigned*)coarse;           // in-place overlay
    int base2 = bk * CAP * 2;                      // bucket base in u32 units
    if (t < BSIZE) { hist[t] = 0; wdeg[t] = 0.f; }
    __syncthreads();
    int cnt = cursor[bk];
    int2 st[EPTF];
#pragma unroll
    for (int i = 0; i < EPTF; i++) {
        int idx = t + i * FTH;
        if (idx < cnt) st[i] = coarse[base + idx];
    }
#pragma unroll
    for (int i = 0; i < EPTF; i++) {
        int idx = t + i * FTH;
        if (idx < cnt) {
            int loc = st[i].x & (BSIZE - 1);
            atomicAdd(&hist[loc], 1);
            atomicAdd(&wdeg[loc], __int_as_float(st[i].y));
        }
    }
    __syncthreads();
    // dinv (deg + 1 self-loop); padded per-col counts for the scan
    int gcol = (bk << BSHIFT) + t;
    int hreal = 0, hpad = 0;
    if (t < BSIZE) {
        float dv = rsqrtf(wdeg[t] + 1.0f);
        if (gcol < NNODES) dinv[gcol] = dv;
        hreal = hist[t];
        hpad = (hreal + 7) & ~7;
        sa[t] = hpad;
    }
    __syncthreads();
    // inclusive scan of padded counts (256 entries); all threads barrier
    int* s = sa; int* d = sb;
    for (int off = 1; off < BSIZE; off <<= 1) {
        if (t < BSIZE) d[t] = s[t] + ((t >= off) ? s[t - off] : 0);
        __syncthreads();
        int* tmp = s; s = d; d = tmp;
    }
    if (t < BSIZE) {
        foff[t] = (t == 0) ? 0 : s[t - 1];
        hist[t] = 0;                               // reuse as fine cursor
        if (gcol < NNODES) rowmeta[gcol] = make_int2(base2 + foff[t], base2 + foff[t] + hpad);
        for (int k = hreal; k < hpad; k++)         // zero-pad tail slots (src=0, w=0)
            csr32[base2 + foff[t] + k] = 0u;
    }
    __syncthreads();
    // in-place permutation: all staged reads happened before this point
#pragma unroll
    for (int i = 0; i < EPTF; i++) {
        int idx = t + i * FTH;
        if (idx < cnt) {
            int loc = st[i].x & (BSIZE - 1);
            unsigned srcn = ((unsigned)st[i].x) >> BSHIFT;
            int pos = foff[loc] + atomicAdd(&hist[loc], 1);
            unsigned wb = (unsigned)__half_as_ushort(__float2half_rn(__int_as_float(st[i].y))) & 0x7FFFu;
            csr32[base2 + pos] = (srcn << 15) | wb;
        }
    }
}

// ---------------------------------------------------------------------------
// MFMA projection: y0h[n, 0..39] = fp16( dinv[n] * (x[n,:] @ WT^T) ).
// Block = 4 waves; each wave: 16 nodes x 48 classes via 16x16x32 bf16 MFMA.
__global__ void __launch_bounds__(256) gemm_mfma_kernel(const float* __restrict__ x,
                                                        const unsigned short* __restrict__ wt,
                                                        const float* __restrict__ dinv,
                                                        __half* __restrict__ y0h) {
    int wv = threadIdx.x >> 6;
    int lane = threadIdx.x & 63;
    int r = lane & 15;           // A row / B col within tile
    int kg = lane >> 4;          // k-group 0..3
    int mbase = blockIdx.x * 64 + wv * 16;
    int anode = mbase + r;
    bool aok = anode < NNODES;
    const float* ap = x + (size_t)anode * NFEAT + kg * 8;

    f32x4 acc0 = {0.f, 0.f, 0.f, 0.f};
    f32x4 acc1 = {0.f, 0.f, 0.f, 0.f};
    f32x4 acc2 = {0.f, 0.f, 0.f, 0.f};
#pragma unroll
    for (int ks = 0; ks < 8; ks++) {
        int k0 = ks * 32 + kg * 8;
        bf16x8 af;
        if (aok) {
            float4 p0 = *(const float4*)(ap + ks * 32);
            float4 p1 = *(const float4*)(ap + ks * 32 + 4);
            af[0] = (short)f2bf(p0.x); af[1] = (short)f2bf(p0.y);
            af[2] = (short)f2bf(p0.z); af[3] = (short)f2bf(p0.w);
            af[4] = (short)f2bf(p1.x); af[5] = (short)f2bf(p1.y);
            af[6] = (short)f2bf(p1.z); af[7] = (short)f2bf(p1.w);
        } else {
            af = bf16x8{0, 0, 0, 0, 0, 0, 0, 0};
        }
        bf16x8 b0 = *(const bf16x8*)(wt + (0 * 16 + r) * NFEAT + k0);
        bf16x8 b1 = *(const bf16x8*)(wt + (1 * 16 + r) * NFEAT + k0);
        bf16x8 b2 = *(const bf16x8*)(wt + (2 * 16 + r) * NFEAT + k0);
        acc0 = __builtin_amdgcn_mfma_f32_16x16x32_bf16(af, b0, acc0, 0, 0, 0);
        acc1 = __builtin_amdgcn_mfma_f32_16x16x32_bf16(af, b1, acc1, 0, 0, 0);
        acc2 = __builtin_amdgcn_mfma_f32_16x16x32_bf16(af, b2, acc2, 0, 0, 0);
    }
    // C/D layout: col(class) = lane&15, row(node) = (lane>>4)*4 + reg
#pragma unroll
    for (int j = 0; j < 4; j++) {
        int node = mbase + kg * 4 + j;
        if (node >= NNODES) continue;
        float dv = dinv[node];
        __half* yr = y0h + (size_t)node * 64;
        yr[r] = __float2half_rn(acc0[j] * dv);
        yr[16 + r] = __float2half_rn(acc1[j] * dv);
        if (r < 8) yr[32 + r] = __float2half_rn(acc2[j] * dv);
    }
}

// ---------------------------------------------------------------------------
// Hop (y' in / y' out): thread = (node, 4 classes), 10 lanes x uint2 per row.
// Block = 320 thr = 32 nodes. Rows are 8-padded -> single 8-deep body, no tail.
// acc = y'[self] + sum_e w_e * y'[src];  store fp16(dinv^2 * acc).
__global__ void __launch_bounds__(320) hop16_kernel(const int2* __restrict__ rowmeta,
                                                    const unsigned* __restrict__ csr,
                                                    const float* __restrict__ dinv,
                                                    const uint2* __restrict__ yin,
                                                    uint2* __restrict__ yout) {
    int tid = threadIdx.x;
    int ln = tid / 10;
    int c4 = tid - ln * 10;
    int n = blockIdx.x * 32 + ln;                  // NNODES == 3125*32, no tail
    float d = dinv[n];
    float dd = d * d;
    int2 rm = rowmeta[n];
    uint2 sv = yin[(size_t)n * ROWU2 + c4];
    float2 s01 = up2(sv.x), s23 = up2(sv.y);
    float a0 = s01.x, a1 = s01.y, a2 = s23.x, a3 = s23.y;
    for (int e = rm.x; e < rm.y; e += 8) {
        unsigned p[8];
        uint2 g[8];
#pragma unroll
        for (int i = 0; i < 8; i++) p[i] = csr[e + i];
#pragma unroll
        for (int i = 0; i < 8; i++) g[i] = yin[(size_t)(p[i] >> 15) * ROWU2 + c4];
#pragma unroll
        for (int i = 0; i < 8; i++) {
            float w = __half2float(__ushort_as_half((unsigned short)(p[i] & 0x7FFFu)));
            float2 u = up2(g[i].x), v = up2(g[i].y);
            a0 += w * u.x; a1 += w * u.y; a2 += w * v.x; a3 += w * v.y;
        }
    }
    yout[(size_t)n * ROWU2 + c4] = make_uint2(pk2(dd * a0, dd * a1), pk2(dd * a2, dd * a3));
}

// ---------------------------------------------------------------------------
// Final hop (y' in / f32 out) with bias + log_softmax fused.
__global__ void __launch_bounds__(320) hop32_kernel(const int2* __restrict__ rowmeta,
                                                    const unsigned* __restrict__ csr,
                                                    const float* __restrict__ dinv,
                                                    const uint2* __restrict__ yin,
                                                    const float* __restrict__ bias,
                                                    float* __restrict__ out) {
    __shared__ float redm[32][10];
    __shared__ float reds[32][10];
    int tid = threadIdx.x;
    int ln = tid / 10;
    int c4 = tid - ln * 10;
    int n = blockIdx.x * 32 + ln;                  // NNODES == 3125*32, no tail
    float d = dinv[n];
    int2 rm = rowmeta[n];
    uint2 sv = yin[(size_t)n * ROWU2 + c4];
    float2 s01 = up2(sv.x), s23 = up2(sv.y);
    float a0 = s01.x, a1 = s01.y, a2 = s23.x, a3 = s23.y;
    for (int e = rm.x; e < rm.y; e += 8) {
        unsigned p[8];
        uint2 g[8];
#pragma unroll
        for (int i = 0; i < 8; i++) p[i] = csr[e + i];
#pragma unroll
        for (int i = 0; i < 8; i++) g[i] = yin[(size_t)(p[i] >> 15) * ROWU2 + c4];
#pragma unroll
        for (int i = 0; i < 8; i++) {
            float w = __half2float(__ushort_as_half((unsigned short)(p[i] & 0x7FFFu)));
            float2 u = up2(g[i].x), v = up2(g[i].y);
            a0 += w * u.x; a1 += w * u.y; a2 += w * v.x; a3 += w * v.y;
        }
    }
    // logits = dinv * acc + bias
    float4 bb = *(const float4*)(bias + c4 * 4);
    float v0 = d * a0 + bb.x, v1 = d * a1 + bb.y, v2 = d * a2 + bb.z, v3 = d * a3 + bb.w;
    // log_softmax over the node's 40 classes (10 lanes x 4)
    redm[ln][c4] = fmaxf(fmaxf(v0, v1), fmaxf(v2, v3));
    __syncthreads();
    if (c4 == 0) {
        float m = redm[ln][0];
#pragma unroll
        for (int j = 1; j < 10; j++) m = fmaxf(m, redm[ln][j]);
        redm[ln][0] = m;
    }
    __syncthreads();
    float m = redm[ln][0];
    reds[ln][c4] = __expf(v0 - m) + __expf(v1 - m) + __expf(v2 - m) + __expf(v3 - m);
    __syncthreads();
    if (c4 == 0) {
        float s = 0.f;
#pragma unroll
        for (int j = 0; j < 10; j++) s += reds[ln][j];
        reds[ln][0] = logf(s);
    }
    __syncthreads();
    float ls = reds[ln][0];
    float4 r = make_float4(v0 - m - ls, v1 - m - ls, v2 - m - ls, v3 - m - ls);
    *(float4*)(out + (size_t)n * NCLASS + c4 * 4) = r;
}

// ---------------------------------------------------------------------------
extern "C" void kernel_launch(void* const* d_in, const int* in_sizes, int n_in,
                              void* d_out, int out_size, void* d_ws, size_t ws_size,
                              hipStream_t stream) {
    const float* x = (const float*)d_in[0];
    const int* eidx = (const int*)d_in[1];
    const float* ew = (const float*)d_in[2];
    const float* W = (const float*)d_in[3];
    const float* b = (const float*)d_in[4];
    float* out = (float*)d_out;

    char* ws = (char*)d_ws;
    size_t off = 0;
    auto alloc = [&](size_t bytes) -> char* {
        char* p = ws + off;
        off += (bytes + 255) & ~(size_t)255;
        return p;
    };
    int* flag = (int*)alloc(sizeof(int));
    int* cursor = (int*)alloc((size_t)NBUCK * 4);
    int2* rowmeta = (int2*)alloc((size_t)NNODES * 8);
    float* dinv = (float*)alloc((size_t)NNODES * 4);
    unsigned short* wt = (unsigned short*)alloc((size_t)48 * 256 * 2);
    int2* gcsr = (int2*)alloc((size_t)NBUCK * CAP * 8);   // coarse -> packed u32 CSR in place
    __half* y0h = (__half*)alloc((size_t)NNODES * 128);
    __half* y1h = (__half*)alloc((size_t)NNODES * 128);

    setup_kernel<<<50, 256, 0, stream>>>(W, wt, cursor, eidx, flag);
    cscatter_kernel<<<NCB, CSTH, 0, stream>>>(eidx, ew, gcsr, cursor, flag);
    fine_kernel<<<NBUCK, FTH, 0, stream>>>(gcsr, cursor, rowmeta, dinv);
    // project features first: y0' = dinv * (x @ W.T)  (propagation commutes)
    gemm_mfma_kernel<<<(NNODES + 63) / 64, 256, 0, stream>>>(x, wt, dinv, y0h);
    const unsigned* csr = (const unsigned*)gcsr;
    // hop 1: y1' = dinv^2 (y0'[self] + A_w y0');  hop 2: out = log_softmax(dinv(...) + b)
    hop16_kernel<<<NNODES / 32, 320, 0, stream>>>(rowmeta, csr, dinv,
                                                  (const uint2*)y0h, (uint2*)y1h);
    hop32_kernel<<<NNODES / 32, 320, 0, stream>>>(rowmeta, csr, dinv,
                                                  (const uint2*)y1h, b, out);
}